// Round 15
// baseline (113.015 us; speedup 1.0000x reference)
//
#include <hip/hip_runtime.h>
#include <hip/hip_bf16.h>

#define Bn  16
#define Cn  256
#define CKn 32
#define Nn  2304   // 48*48

typedef __attribute__((ext_vector_type(16))) float f32x16;
typedef __attribute__((ext_vector_type(8)))  short bf16x8;
typedef __attribute__((ext_vector_type(4)))  int   i32x4;

union FragU { unsigned u[4]; bf16x8 v; };
union KU    { i32x4 i; bf16x8 v; };

__device__ __forceinline__ unsigned pk(float lo, float hi){
  unsigned a = (unsigned)__bfloat16_as_ushort(__float2bfloat16(lo));
  unsigned b = (unsigned)__bfloat16_as_ushort(__float2bfloat16(hi));
  return a | (b << 16);
}

// D-layout -> A/B-frag halfswap via v_permlane32_swap_b32 (validated R8):
// A_new = {A_lo, B_lo} = w0,  B_new = {A_hi, B_hi} = w2.
__device__ __forceinline__ void halfswap(unsigned A, unsigned Bv, int /*h*/,
                                         unsigned &w0, unsigned &w2){
  asm("v_permlane32_swap_b32 %0, %1" : "+v"(A), "+v"(Bv));
  w0 = A; w2 = Bv;
}

__device__ __forceinline__ void conv_store(const f32x16& a, int h, int l,
                                           __hip_bfloat16* dst0, size_t stride){
  unsigned Wp[8];
  #pragma unroll
  for (int q = 0; q < 8; ++q) Wp[q] = pk(a[2*q], a[2*q+1]);
  #pragma unroll
  for (int k2 = 0; k2 < 2; ++k2){
    FragU u;
    halfswap(Wp[4*k2+0], Wp[4*k2+2], h, u.u[0], u.u[2]);
    halfswap(Wp[4*k2+1], Wp[4*k2+3], h, u.u[1], u.u[3]);
    *(bf16x8*)(dst0 + k2*stride + l*8) = u.v;
  }
}

// async global -> LDS, 16B per lane; LDS dest is wave-uniform base + lane*16
__device__ __forceinline__ void gld16(const void* g, void* l){
  __builtin_amdgcn_global_load_lds(
      (__attribute__((address_space(1))) void*)const_cast<void*>(g),
      (__attribute__((address_space(3))) void*)l, 16, 0, 0);
}

// ---------------------------------------------------------------------------
// Pack weights+bias into MFMA frag layout. Wf[kt 0..16][tile 0..9][512] bf16.
// ---------------------------------------------------------------------------
__global__ __launch_bounds__(64) void wfrag_kernel(
    const float* __restrict__ Wq, const float* __restrict__ bq,
    const float* __restrict__ Wk, const float* __restrict__ bk,
    const float* __restrict__ Wv, const float* __restrict__ bv,
    __hip_bfloat16* __restrict__ Wf){
  const int kt = blockIdx.x / 10, tile = blockIdx.x % 10;
  const int l = threadIdx.x, lo = l & 31, h = l >> 5;
  __hip_bfloat16* dst = Wf + (size_t)(kt*10 + tile)*512 + l*8;
  if (kt < 16){
    const float* Wp; int row;
    if (tile < 8)       { Wp = Wv; row = tile*32 + lo; }
    else if (tile == 8) { Wp = Wq; row = lo; }
    else                { Wp = Wk; row = lo; }
    #pragma unroll
    for (int e = 0; e < 8; ++e)
      dst[e] = __float2bfloat16(Wp[(size_t)row*Cn + kt*16 + 8*h + e]);
  } else {
    const float* bp = tile < 8 ? bv : (tile == 8 ? bq : bk);
    int row = tile < 8 ? tile*32 + lo : lo;
    #pragma unroll
    for (int e = 0; e < 8; ++e)
      dst[e] = __float2bfloat16((h == 0 && e == 0) ? bp[row] : 0.f);
  }
}

// ---------------------------------------------------------------------------
// Projection GEMM, 1152 x 64-thr blocks (measured: non-attn ~16.0us total).
// Q pre-scaled by log2(e)/sqrt(C).
// ---------------------------------------------------------------------------
__global__ __launch_bounds__(64) void proj_kernel(
    const float* __restrict__ x, const __hip_bfloat16* __restrict__ Wf,
    __hip_bfloat16* __restrict__ Qf, __hip_bfloat16* __restrict__ Kf,
    __hip_bfloat16* __restrict__ Vf){
  const int u = blockIdx.x;                 // 1152 = 16b x 72 n32
  const int b = u / 72, n32 = u % 72;
  const int l = threadIdx.x & 63, lo = l & 31, h = l >> 5;
  const int n0 = n32*32;

  f32x16 acc[10];
  #pragma unroll
  for (int t = 0; t < 10; ++t)
    #pragma unroll
    for (int r = 0; r < 16; ++r) acc[t][r] = 0.f;

  const float* xb = x + (size_t)b*Cn*Nn + n0 + lo;

  #pragma unroll 1
  for (int kt = 0; kt < 16; ++kt){
    FragU xf;
    float v[8];
    #pragma unroll
    for (int e = 0; e < 8; ++e) v[e] = xb[(size_t)(kt*16 + 8*h + e)*Nn];
    #pragma unroll
    for (int q = 0; q < 4; ++q) xf.u[q] = pk(v[2*q], v[2*q+1]);
    const __hip_bfloat16* wfp = Wf + (size_t)(kt*10)*512 + l*8;
    #pragma unroll
    for (int t = 0; t < 10; ++t){
      bf16x8 wf = *(const bf16x8*)(wfp + t*512);
      if (t < 8) acc[t] = __builtin_amdgcn_mfma_f32_32x32x16_bf16(xf.v, wf, acc[t], 0,0,0);
      else       acc[t] = __builtin_amdgcn_mfma_f32_32x32x16_bf16(wf, xf.v, acc[t], 0,0,0);
    }
  }
  { // bias k-step
    FragU xf;
    xf.u[0] = h ? 0u : 0x00003f80u;
    xf.u[1] = xf.u[2] = xf.u[3] = 0u;
    const __hip_bfloat16* wfp = Wf + (size_t)(16*10)*512 + l*8;
    #pragma unroll
    for (int t = 0; t < 10; ++t){
      bf16x8 wf = *(const bf16x8*)(wfp + t*512);
      if (t < 8) acc[t] = __builtin_amdgcn_mfma_f32_32x32x16_bf16(xf.v, wf, acc[t], 0,0,0);
      else       acc[t] = __builtin_amdgcn_mfma_f32_32x32x16_bf16(wf, xf.v, acc[t], 0,0,0);
    }
  }

  // fold softmax scale into Q: k1 = log2(e)/sqrt(256)
  #pragma unroll
  for (int r = 0; r < 16; ++r) acc[8][r] *= 0.09016844f;

  #pragma unroll
  for (int t = 0; t < 8; ++t)
    conv_store(acc[t], h, l, Vf + (((size_t)b*144 + n32*2)*8 + t)*512, 8*512);
  conv_store(acc[8], h, l, Qf + ((size_t)b*72 + n32)*2*512, 512);
  conv_store(acc[9], h, l, Kf + ((size_t)b*72 + n32)*2*512, 512);
}

// ---------------------------------------------------------------------------
// Attention R15: BARRIER-FREE 1-wave blocks. Block = 64 thr = 32q x ch-half;
// grid 2304 (8-XCD swizzle, 9 blocks/CU). Private 16KB V buffer per block,
// single-buffered: stage(t) issues early, QK+softmax cover the L2 latency,
// counted vmcnt gates use. Zero s_barrier; the 2 waves/SIMD now advance with
// UNCORRELATED stall phases instead of barrier lockstep.
// Ledger (steady state): entry outstanding = K(t) 4. +16 V, +4 K(t+1) = 24;
// vmcnt(20) -> K(t) landed (QK); vmcnt(4) -> V(t) landed, K(t+1) flying (PV).
// ---------------------------------------------------------------------------
__global__ __launch_bounds__(64, 2) void attn_kernel(
    const __hip_bfloat16* __restrict__ Qf, const __hip_bfloat16* __restrict__ Kf,
    const __hip_bfloat16* __restrict__ Vf, const float* __restrict__ x,
    const float* __restrict__ gptr, float* __restrict__ out){
  __shared__ __align__(16) char smem[16384];   // V single buffer
  const int xcd = blockIdx.x & 7, seq = blockIdx.x >> 3;   // 2304 = 8*288
  const int b   = xcd*2 + (seq / 144);                     // 2 batches per XCD
  const int rem = seq % 144;
  const int qt  = rem >> 1;                                // 0..71 (32q tile)
  const int ch  = rem & 1;                                 // channel half
  const int l = threadIdx.x & 63, lo = l & 31, h = l >> 5;

  const char* vlane = (const char*)Vf + ((size_t)b*1152 + ch*4)*1024 + (size_t)l*16;
  const char* klane = (const char*)Kf + (size_t)b*147456 + (size_t)l*16;

  auto stageV = [&](int jt){               // 16 gld16 rounds (16KB, one wave)
    const char* gt = vlane + (size_t)jt*32768;
    #pragma unroll
    for (int f = 0; f < 16; ++f)
      gld16(gt + (f >> 2)*8192 + (f & 3)*1024, smem + f*1024);
  };
  auto kload = [&](int jn, KU (&kf)[2][2]){ // 4 asm global loads (K tile->regs)
    const char* ka = klane + (size_t)jn*4096;
    asm volatile("global_load_dwordx4 %0, %1, off"             : "=v"(kf[0][0].i) : "v"(ka) : "memory");
    asm volatile("global_load_dwordx4 %0, %1, off offset:1024" : "=v"(kf[0][1].i) : "v"(ka) : "memory");
    asm volatile("global_load_dwordx4 %0, %1, off offset:2048" : "=v"(kf[1][0].i) : "v"(ka) : "memory");
    asm volatile("global_load_dwordx4 %0, %1, off offset:3072" : "=v"(kf[1][1].i) : "v"(ka) : "memory");
  };

  // Q -> regs
  bf16x8 qf[2];
  #pragma unroll
  for (int kt = 0; kt < 2; ++kt)
    qf[kt] = *(const bf16x8*)(Qf + (((size_t)b*72 + qt)*2 + kt)*512 + l*8);

  f32x16 acc4[4];
  #pragma unroll
  for (int c = 0; c < 4; ++c)
    #pragma unroll
    for (int r = 0; r < 16; ++r) acc4[c][r] = 0.f;
  float lsum = 0.f;

  KU kfA[2][2], kfB[2][2];
  kload(0, kfA);                            // 4 outstanding at loop entry

  auto body = [&](int jt, KU (&cur)[2][2], KU (&nxt)[2][2]){
    // prior PV ds_reads retired before overwriting the single V buffer
    asm volatile("s_waitcnt lgkmcnt(0)" ::: "memory");
    stageV(jt);                             // +16 -> 20
    int jn = jt + 1; if (jn >= 36) jn = 0;
    kload(jn, nxt);                         // +4 -> 24
    asm volatile("s_waitcnt vmcnt(20)" ::: "memory");   // K(t) landed
    __builtin_amdgcn_sched_barrier(0);      // rule 18: pin MFMA below wait

    f32x16 z;
    #pragma unroll
    for (int r = 0; r < 16; ++r) z[r] = 0.f;
    f32x16 S0 = __builtin_amdgcn_mfma_f32_32x32x16_bf16(cur[0][0].v, qf[0], z, 0,0,0);
    S0 = __builtin_amdgcn_mfma_f32_32x32x16_bf16(cur[0][1].v, qf[1], S0, 0,0,0);
    f32x16 S1 = __builtin_amdgcn_mfma_f32_32x32x16_bf16(cur[1][0].v, qf[0], z, 0,0,0);
    S1 = __builtin_amdgcn_mfma_f32_32x32x16_bf16(cur[1][1].v, qf[1], S1, 0,0,0);

    // fixed-max softmax, raw v_exp_f32; covers V(t) L2 latency
    FragU pf[4];
    float s0 = 0.f, s1 = 0.f, s2 = 0.f, s3 = 0.f;
    {
      unsigned Wp[8];
      #pragma unroll
      for (int q = 0; q < 4; ++q){
        float p0 = __builtin_amdgcn_exp2f(S0[2*q]);
        float p1 = __builtin_amdgcn_exp2f(S0[2*q+1]);
        s0 += p0 + p1; Wp[q] = pk(p0, p1);
      }
      #pragma unroll
      for (int q = 4; q < 8; ++q){
        float p0 = __builtin_amdgcn_exp2f(S0[2*q]);
        float p1 = __builtin_amdgcn_exp2f(S0[2*q+1]);
        s1 += p0 + p1; Wp[q] = pk(p0, p1);
      }
      halfswap(Wp[0], Wp[2], h, pf[0].u[0], pf[0].u[2]);
      halfswap(Wp[1], Wp[3], h, pf[0].u[1], pf[0].u[3]);
      halfswap(Wp[4], Wp[6], h, pf[1].u[0], pf[1].u[2]);
      halfswap(Wp[5], Wp[7], h, pf[1].u[1], pf[1].u[3]);
    }
    {
      unsigned Wp[8];
      #pragma unroll
      for (int q = 0; q < 4; ++q){
        float p0 = __builtin_amdgcn_exp2f(S1[2*q]);
        float p1 = __builtin_amdgcn_exp2f(S1[2*q+1]);
        s2 += p0 + p1; Wp[q] = pk(p0, p1);
      }
      #pragma unroll
      for (int q = 4; q < 8; ++q){
        float p0 = __builtin_amdgcn_exp2f(S1[2*q]);
        float p1 = __builtin_amdgcn_exp2f(S1[2*q+1]);
        s3 += p0 + p1; Wp[q] = pk(p0, p1);
      }
      halfswap(Wp[0], Wp[2], h, pf[2].u[0], pf[2].u[2]);
      halfswap(Wp[1], Wp[3], h, pf[2].u[1], pf[2].u[3]);
      halfswap(Wp[4], Wp[6], h, pf[3].u[0], pf[3].u[2]);
      halfswap(Wp[5], Wp[7], h, pf[3].u[1], pf[3].u[3]);
    }
    lsum += (s0 + s1) + (s2 + s3);

    asm volatile("s_waitcnt vmcnt(4)" ::: "memory");    // V(t) landed; K(t+1) flying
    __builtin_amdgcn_sched_barrier(0);
    #pragma unroll
    for (int js = 0; js < 4; ++js){
      #pragma unroll
      for (int c = 0; c < 4; ++c){
        bf16x8 v = *(const bf16x8*)(smem + (js*4 + c)*1024 + l*16);
        acc4[c] = __builtin_amdgcn_mfma_f32_32x32x16_bf16(v, pf[js].v, acc4[c], 0,0,0);
      }
    }
  };

  #pragma unroll 1
  for (int jt = 0; jt < 36; jt += 2){
    body(jt,   kfA, kfB);
    body(jt+1, kfB, kfA);
  }

  // epilogue: reduce lsum halves, scale, direct coalesced store
  lsum += __shfl_xor(lsum, 32);
  const float sc = gptr[0] / lsum;
  const int ibase = qt*32;
  #pragma unroll
  for (int c = 0; c < 4; ++c){
    #pragma unroll
    for (int r = 0; r < 16; ++r){
      const int cg = ch*128 + c*32 + (r & 3) + 8*(r >> 2) + 4*h;
      const size_t idx = ((size_t)b*Cn + cg)*Nn + ibase + lo;
      out[idx] = acc4[c][r]*sc + x[idx];
    }
  }
}

extern "C" void kernel_launch(void* const* d_in, const int* in_sizes, int n_in,
                              void* d_out, int out_size, void* d_ws, size_t ws_size,
                              hipStream_t stream) {
  const float* x     = (const float*)d_in[0];
  const float* Wq    = (const float*)d_in[1];
  const float* bq    = (const float*)d_in[2];
  const float* Wk    = (const float*)d_in[3];
  const float* bk    = (const float*)d_in[4];
  const float* Wv    = (const float*)d_in[5];
  const float* bv    = (const float*)d_in[6];
  const float* gamma = (const float*)d_in[7];
  float* out = (float*)d_out;

  __hip_bfloat16* Qf = (__hip_bfloat16*)d_ws;          // 16*72*2*512
  __hip_bfloat16* Kf = Qf + (size_t)Bn*72*2*512;
  __hip_bfloat16* Vf = Kf + (size_t)Bn*72*2*512;       // 16*144*8*512
  __hip_bfloat16* Wf = Vf + (size_t)Bn*144*8*512;      // 17*10*512

  wfrag_kernel<<<dim3(170), dim3(64), 0, stream>>>(Wq, bq, Wk, bk, Wv, bv, Wf);
  proj_kernel<<<dim3(1152), dim3(64), 0, stream>>>(x, Wf, Qf, Kf, Vf);
  attn_kernel<<<dim3(2304), dim3(64), 0, stream>>>(Qf, Kf, Vf, x, gamma, out);
}

// Round 17
// 100.848 us; speedup vs baseline: 1.1206x; 1.1206x over previous
//
#include <hip/hip_runtime.h>
#include <hip/hip_bf16.h>

#define Bn  16
#define Cn  256
#define CKn 32
#define Nn  2304   // 48*48

typedef __attribute__((ext_vector_type(16))) float f32x16;
typedef __attribute__((ext_vector_type(8)))  short bf16x8;
typedef __attribute__((ext_vector_type(4)))  int   i32x4;

union FragU { unsigned u[4]; bf16x8 v; };
union KU    { i32x4 i; bf16x8 v; };

__device__ __forceinline__ unsigned pk(float lo, float hi){
  unsigned a = (unsigned)__bfloat16_as_ushort(__float2bfloat16(lo));
  unsigned b = (unsigned)__bfloat16_as_ushort(__float2bfloat16(hi));
  return a | (b << 16);
}

// D-layout -> A/B-frag halfswap via v_permlane32_swap_b32 (validated R8):
// A_new = {A_lo, B_lo} = w0,  B_new = {A_hi, B_hi} = w2.
__device__ __forceinline__ void halfswap(unsigned A, unsigned Bv, int /*h*/,
                                         unsigned &w0, unsigned &w2){
  asm("v_permlane32_swap_b32 %0, %1" : "+v"(A), "+v"(Bv));
  w0 = A; w2 = Bv;
}

__device__ __forceinline__ void conv_store(const f32x16& a, int h, int l,
                                           __hip_bfloat16* dst0, size_t stride){
  unsigned Wp[8];
  #pragma unroll
  for (int q = 0; q < 8; ++q) Wp[q] = pk(a[2*q], a[2*q+1]);
  #pragma unroll
  for (int k2 = 0; k2 < 2; ++k2){
    FragU u;
    halfswap(Wp[4*k2+0], Wp[4*k2+2], h, u.u[0], u.u[2]);
    halfswap(Wp[4*k2+1], Wp[4*k2+3], h, u.u[1], u.u[3]);
    *(bf16x8*)(dst0 + k2*stride + l*8) = u.v;
  }
}

// async global -> LDS, 16B per lane; LDS dest is wave-uniform base + lane*16
__device__ __forceinline__ void gld16(const void* g, void* l){
  __builtin_amdgcn_global_load_lds(
      (__attribute__((address_space(1))) void*)const_cast<void*>(g),
      (__attribute__((address_space(3))) void*)l, 16, 0, 0);
}

// ---------------------------------------------------------------------------
// Pack weights+bias into MFMA frag layout. Wf[kt 0..16][tile 0..9][512] bf16.
// ---------------------------------------------------------------------------
__global__ __launch_bounds__(64) void wfrag_kernel(
    const float* __restrict__ Wq, const float* __restrict__ bq,
    const float* __restrict__ Wk, const float* __restrict__ bk,
    const float* __restrict__ Wv, const float* __restrict__ bv,
    __hip_bfloat16* __restrict__ Wf){
  const int kt = blockIdx.x / 10, tile = blockIdx.x % 10;
  const int l = threadIdx.x, lo = l & 31, h = l >> 5;
  __hip_bfloat16* dst = Wf + (size_t)(kt*10 + tile)*512 + l*8;
  if (kt < 16){
    const float* Wp; int row;
    if (tile < 8)       { Wp = Wv; row = tile*32 + lo; }
    else if (tile == 8) { Wp = Wq; row = lo; }
    else                { Wp = Wk; row = lo; }
    #pragma unroll
    for (int e = 0; e < 8; ++e)
      dst[e] = __float2bfloat16(Wp[(size_t)row*Cn + kt*16 + 8*h + e]);
  } else {
    const float* bp = tile < 8 ? bv : (tile == 8 ? bq : bk);
    int row = tile < 8 ? tile*32 + lo : lo;
    #pragma unroll
    for (int e = 0; e < 8; ++e)
      dst[e] = __float2bfloat16((h == 0 && e == 0) ? bp[row] : 0.f);
  }
}

// ---------------------------------------------------------------------------
// Projection GEMM, 1152 x 64-thr blocks (measured: non-attn ~16.0us total).
// Q pre-scaled by log2(e)/sqrt(C).
// ---------------------------------------------------------------------------
__global__ __launch_bounds__(64) void proj_kernel(
    const float* __restrict__ x, const __hip_bfloat16* __restrict__ Wf,
    __hip_bfloat16* __restrict__ Qf, __hip_bfloat16* __restrict__ Kf,
    __hip_bfloat16* __restrict__ Vf){
  const int u = blockIdx.x;                 // 1152 = 16b x 72 n32
  const int b = u / 72, n32 = u % 72;
  const int l = threadIdx.x & 63, lo = l & 31, h = l >> 5;
  const int n0 = n32*32;

  f32x16 acc[10];
  #pragma unroll
  for (int t = 0; t < 10; ++t)
    #pragma unroll
    for (int r = 0; r < 16; ++r) acc[t][r] = 0.f;

  const float* xb = x + (size_t)b*Cn*Nn + n0 + lo;

  #pragma unroll 1
  for (int kt = 0; kt < 16; ++kt){
    FragU xf;
    float v[8];
    #pragma unroll
    for (int e = 0; e < 8; ++e) v[e] = xb[(size_t)(kt*16 + 8*h + e)*Nn];
    #pragma unroll
    for (int q = 0; q < 4; ++q) xf.u[q] = pk(v[2*q], v[2*q+1]);
    const __hip_bfloat16* wfp = Wf + (size_t)(kt*10)*512 + l*8;
    #pragma unroll
    for (int t = 0; t < 10; ++t){
      bf16x8 wf = *(const bf16x8*)(wfp + t*512);
      if (t < 8) acc[t] = __builtin_amdgcn_mfma_f32_32x32x16_bf16(xf.v, wf, acc[t], 0,0,0);
      else       acc[t] = __builtin_amdgcn_mfma_f32_32x32x16_bf16(wf, xf.v, acc[t], 0,0,0);
    }
  }
  { // bias k-step
    FragU xf;
    xf.u[0] = h ? 0u : 0x00003f80u;
    xf.u[1] = xf.u[2] = xf.u[3] = 0u;
    const __hip_bfloat16* wfp = Wf + (size_t)(16*10)*512 + l*8;
    #pragma unroll
    for (int t = 0; t < 10; ++t){
      bf16x8 wf = *(const bf16x8*)(wfp + t*512);
      if (t < 8) acc[t] = __builtin_amdgcn_mfma_f32_32x32x16_bf16(xf.v, wf, acc[t], 0,0,0);
      else       acc[t] = __builtin_amdgcn_mfma_f32_32x32x16_bf16(wf, xf.v, acc[t], 0,0,0);
    }
  }

  // fold softmax scale into Q: k1 = log2(e)/sqrt(256)
  #pragma unroll
  for (int r = 0; r < 16; ++r) acc[8][r] *= 0.09016844f;

  #pragma unroll
  for (int t = 0; t < 8; ++t)
    conv_store(acc[t], h, l, Vf + (((size_t)b*144 + n32*2)*8 + t)*512, 8*512);
  conv_store(acc[8], h, l, Qf + ((size_t)b*72 + n32)*2*512, 512);
  conv_store(acc[9], h, l, Kf + ((size_t)b*72 + n32)*2*512, 512);
}

// ---------------------------------------------------------------------------
// Attention R17 = exact R11 (best measured attn: 82.6us). 3-wave (192-thr)
// blocks of 96q x ch-half; grid 768 = exactly 3 blocks/CU. V triple-buffered
// (stage 2 ahead, 6 uniform gld16 rounds), K 1-ahead in regs (asm dwordx4),
// counted vmcnt(6) + ONE barrier/iter, fixed-max softmax with raw v_exp_f32.
// No setprio (R13: -13%). No softmax pipelining (R10/R12: spills).
// ---------------------------------------------------------------------------
__global__ __launch_bounds__(192, 2) void attn_kernel(
    const __hip_bfloat16* __restrict__ Qf, const __hip_bfloat16* __restrict__ Kf,
    const __hip_bfloat16* __restrict__ Vf, const float* __restrict__ x,
    const float* __restrict__ gptr, float* __restrict__ out){
  __shared__ __align__(16) char smem[49152];   // V 3 x 16KB
  const int xcd = blockIdx.x & 7, seq = blockIdx.x >> 3;   // 768 = 8*96
  const int b    = xcd*2 + (seq / 48);                     // 2 batches per XCD
  const int rem  = seq % 48;
  const int q24  = rem >> 1;                               // 0..23 (96q block)
  const int ch   = rem & 1;                                // channel half
  const int tid = threadIdx.x;
  const int w = tid >> 6, l = tid & 63, lo = l & 31, h = l >> 5;

  const char* vlane = (const char*)Vf + ((size_t)b*1152 + ch*4)*1024 + (size_t)l*16;
  const char* klane = (const char*)Kf + (size_t)b*147456 + (size_t)l*16;

  auto stageV = [&](int jt, int buf){      // 6 uniform gld16 rounds (16KB)
    const char* gt = vlane + (size_t)jt*32768;
    #pragma unroll
    for (int r = 0; r < 5; ++r){
      const int f = r*3 + w;               // frags 0..14
      gld16(gt + (f >> 2)*8192 + (f & 3)*1024, smem + buf*16384 + f*1024);
    }
    gld16(gt + 3*8192 + 3*1024, smem + buf*16384 + 15*1024);  // frag 15, dup x3
  };
  auto kload = [&](int jn, KU (&kf)[2][2]){ // 4 asm global loads (K tile->regs)
    const char* ka = klane + (size_t)jn*4096;
    asm volatile("global_load_dwordx4 %0, %1, off"             : "=v"(kf[0][0].i) : "v"(ka) : "memory");
    asm volatile("global_load_dwordx4 %0, %1, off offset:1024" : "=v"(kf[0][1].i) : "v"(ka) : "memory");
    asm volatile("global_load_dwordx4 %0, %1, off offset:2048" : "=v"(kf[1][0].i) : "v"(ka) : "memory");
    asm volatile("global_load_dwordx4 %0, %1, off offset:3072" : "=v"(kf[1][1].i) : "v"(ka) : "memory");
  };

  // Q -> regs (it-tile = q24*3 + w)
  bf16x8 qf[2];
  #pragma unroll
  for (int kt = 0; kt < 2; ++kt)
    qf[kt] = *(const bf16x8*)(Qf + (((size_t)b*72 + q24*3 + w)*2 + kt)*512 + l*8);

  f32x16 acc4[4];
  #pragma unroll
  for (int c = 0; c < 4; ++c)
    #pragma unroll
    for (int r = 0; r < 16; ++r) acc4[c][r] = 0.f;
  float lsum = 0.f;

  KU kfA[2][2], kfB[2][2];

  // prologue: K(0) -> kfA; V(0)->buf0, V(1)->buf1   (16 vm-ops outstanding)
  kload(0, kfA);
  stageV(0, 0);
  stageV(1, 1);

  // body(jt): wait V(jt)+K(jt) (leave V(jt+1) flying); barrier;
  //           kload(jt+1), stageV(jt+2); QK; softmax (raw exp2); PV.
  auto body = [&](int jt, KU (&cur)[2][2], KU (&nxt)[2][2], int vb){
    asm volatile("s_waitcnt vmcnt(6)" ::: "memory");
    __builtin_amdgcn_s_barrier();
    __builtin_amdgcn_sched_barrier(0);
    int jn = jt + 1; if (jn >= 36) jn -= 36;
    kload(jn, nxt);
    int j2 = jt + 2; if (j2 >= 36) j2 -= 36;
    int sb = vb + 2; if (sb >= 3) sb -= 3;
    stageV(j2, sb);

    f32x16 z;
    #pragma unroll
    for (int r = 0; r < 16; ++r) z[r] = 0.f;
    f32x16 S0 = __builtin_amdgcn_mfma_f32_32x32x16_bf16(cur[0][0].v, qf[0], z, 0,0,0);
    S0 = __builtin_amdgcn_mfma_f32_32x32x16_bf16(cur[0][1].v, qf[1], S0, 0,0,0);
    f32x16 S1 = __builtin_amdgcn_mfma_f32_32x32x16_bf16(cur[1][0].v, qf[0], z, 0,0,0);
    S1 = __builtin_amdgcn_mfma_f32_32x32x16_bf16(cur[1][1].v, qf[1], S1, 0,0,0);

    // fixed-max softmax, raw v_exp_f32, treed partial sums
    FragU pf[4];
    float s0 = 0.f, s1 = 0.f, s2 = 0.f, s3 = 0.f;
    {
      unsigned Wp[8];
      #pragma unroll
      for (int q = 0; q < 4; ++q){
        float p0 = __builtin_amdgcn_exp2f(S0[2*q]);
        float p1 = __builtin_amdgcn_exp2f(S0[2*q+1]);
        s0 += p0 + p1; Wp[q] = pk(p0, p1);
      }
      #pragma unroll
      for (int q = 4; q < 8; ++q){
        float p0 = __builtin_amdgcn_exp2f(S0[2*q]);
        float p1 = __builtin_amdgcn_exp2f(S0[2*q+1]);
        s1 += p0 + p1; Wp[q] = pk(p0, p1);
      }
      halfswap(Wp[0], Wp[2], h, pf[0].u[0], pf[0].u[2]);
      halfswap(Wp[1], Wp[3], h, pf[0].u[1], pf[0].u[3]);
      halfswap(Wp[4], Wp[6], h, pf[1].u[0], pf[1].u[2]);
      halfswap(Wp[5], Wp[7], h, pf[1].u[1], pf[1].u[3]);
    }
    {
      unsigned Wp[8];
      #pragma unroll
      for (int q = 0; q < 4; ++q){
        float p0 = __builtin_amdgcn_exp2f(S1[2*q]);
        float p1 = __builtin_amdgcn_exp2f(S1[2*q+1]);
        s2 += p0 + p1; Wp[q] = pk(p0, p1);
      }
      #pragma unroll
      for (int q = 4; q < 8; ++q){
        float p0 = __builtin_amdgcn_exp2f(S1[2*q]);
        float p1 = __builtin_amdgcn_exp2f(S1[2*q+1]);
        s3 += p0 + p1; Wp[q] = pk(p0, p1);
      }
      halfswap(Wp[0], Wp[2], h, pf[2].u[0], pf[2].u[2]);
      halfswap(Wp[1], Wp[3], h, pf[2].u[1], pf[2].u[3]);
      halfswap(Wp[4], Wp[6], h, pf[3].u[0], pf[3].u[2]);
      halfswap(Wp[5], Wp[7], h, pf[3].u[1], pf[3].u[3]);
    }
    lsum += (s0 + s1) + (s2 + s3);

    const char* cbV = smem + vb*16384;
    #pragma unroll
    for (int js = 0; js < 4; ++js){
      #pragma unroll
      for (int c = 0; c < 4; ++c){
        bf16x8 v = *(const bf16x8*)(cbV + (js*4 + c)*1024 + l*16);
        acc4[c] = __builtin_amdgcn_mfma_f32_32x32x16_bf16(v, pf[js].v, acc4[c], 0,0,0);
      }
    }
  };

  #pragma unroll 1
  for (int jt = 0; jt < 36; jt += 6){
    body(jt+0, kfA, kfB, 0);
    body(jt+1, kfB, kfA, 1);
    body(jt+2, kfA, kfB, 2);
    body(jt+3, kfB, kfA, 0);
    body(jt+4, kfA, kfB, 1);
    body(jt+5, kfB, kfA, 2);
  }

  // epilogue: reduce lsum halves, scale, direct coalesced store
  lsum += __shfl_xor(lsum, 32);
  const float sc = gptr[0] / lsum;
  const int ibase = q24*96 + w*32;
  #pragma unroll
  for (int c = 0; c < 4; ++c){
    #pragma unroll
    for (int r = 0; r < 16; ++r){
      const int cg = ch*128 + c*32 + (r & 3) + 8*(r >> 2) + 4*h;
      const size_t idx = ((size_t)b*Cn + cg)*Nn + ibase + lo;
      out[idx] = acc4[c][r]*sc + x[idx];
    }
  }
}

extern "C" void kernel_launch(void* const* d_in, const int* in_sizes, int n_in,
                              void* d_out, int out_size, void* d_ws, size_t ws_size,
                              hipStream_t stream) {
  const float* x     = (const float*)d_in[0];
  const float* Wq    = (const float*)d_in[1];
  const float* bq    = (const float*)d_in[2];
  const float* Wk    = (const float*)d_in[3];
  const float* bk    = (const float*)d_in[4];
  const float* Wv    = (const float*)d_in[5];
  const float* bv    = (const float*)d_in[6];
  const float* gamma = (const float*)d_in[7];
  float* out = (float*)d_out;

  __hip_bfloat16* Qf = (__hip_bfloat16*)d_ws;          // 16*72*2*512
  __hip_bfloat16* Kf = Qf + (size_t)Bn*72*2*512;
  __hip_bfloat16* Vf = Kf + (size_t)Bn*72*2*512;       // 16*144*8*512
  __hip_bfloat16* Wf = Vf + (size_t)Bn*144*8*512;      // 17*10*512

  wfrag_kernel<<<dim3(170), dim3(64), 0, stream>>>(Wq, bq, Wk, bk, Wv, bv, Wf);
  proj_kernel<<<dim3(1152), dim3(64), 0, stream>>>(x, Wf, Qf, Kf, Vf);
  attn_kernel<<<dim3(768), dim3(192), 0, stream>>>(Qf, Kf, Vf, x, gamma, out);
}